// Round 12
// baseline (195.018 us; speedup 1.0000x reference)
//
#include <hip/hip_runtime.h>
#include <hip/hip_bf16.h>
#include <stdint.h>

typedef __bf16 bf16_t;
typedef __bf16 bf16x8 __attribute__((ext_vector_type(8)));
typedef __bf16 bf16x4 __attribute__((ext_vector_type(4)));
typedef float f32x4 __attribute__((ext_vector_type(4)));

#define GLD_LDS16(src, dst)                                                              \
  __builtin_amdgcn_global_load_lds((const __attribute__((address_space(1))) void*)(src), \
                                   (__attribute__((address_space(3))) void*)(dst), 16, 0, 0)

// ---------------------------------------------------------------------------
// fp32 -> bf16 convert, ALL tensors in one launch, 32 B/lane (2x float4 in,
// bf16x8 out). blockIdx.y = segment.
// ---------------------------------------------------------------------------
struct CvtArgs {
  const float* src[7];
  bf16_t* dst[7];
  long n4[7];  // count of float4 elements (even for all segments)
};

__global__ __launch_bounds__(256) void cvt_all(CvtArgs a) {
  const int seg = blockIdx.y;
  const float4* __restrict__ in4 = (const float4*)a.src[seg];
  bf16_t* __restrict__ out = a.dst[seg];
  const long n4 = a.n4[seg];
  long i = ((long)blockIdx.x * blockDim.x + threadIdx.x) * 2;
  const long stride = (long)gridDim.x * blockDim.x * 2;
  for (; i + 1 < n4; i += stride) {
    float4 va = in4[i];
    float4 vb = in4[i + 1];
    bf16x8 o;
    o[0] = (bf16_t)va.x; o[1] = (bf16_t)va.y; o[2] = (bf16_t)va.z; o[3] = (bf16_t)va.w;
    o[4] = (bf16_t)vb.x; o[5] = (bf16_t)vb.y; o[6] = (bf16_t)vb.z; o[7] = (bf16_t)vb.w;
    *(bf16x8*)(out + i * 4) = o;
  }
}

// ---------------------------------------------------------------------------
// Causal row softmax, in-place, bounded: row i only touches
// j < jmax = (floor(i/128)+1)*128 (PV's KBOUND never reads past jmax).
// ---------------------------------------------------------------------------
__global__ __launch_bounds__(256) void softmax_causal(bf16_t* __restrict__ S, int n, long sB) {
  const int i = blockIdx.x;
  const int z = blockIdx.y;
  bf16_t* row = S + (long)z * sB + (long)i * n;
  const int t = threadIdx.x;
  const int j0 = t << 3;
  const int jmax = ((i >> 7) + 1) << 7;
  const bool active = j0 < jmax;

  float vals[8];
  float mx = -3.0e38f;
  if (active) {
    bf16x8 vv = ((const bf16x8*)row)[t];
#pragma unroll
    for (int e = 0; e < 8; ++e) {
      float v = (j0 + e <= i) ? (float)vv[e] : -3.0e38f;
      vals[e] = v;
      mx = fmaxf(mx, v);
    }
  }
#pragma unroll
  for (int off = 32; off; off >>= 1) mx = fmaxf(mx, __shfl_xor(mx, off));
  __shared__ float redm[4];
  if ((t & 63) == 0) redm[t >> 6] = mx;
  __syncthreads();
  mx = fmaxf(fmaxf(redm[0], redm[1]), fmaxf(redm[2], redm[3]));

  float sum = 0.f;
  if (active) {
#pragma unroll
    for (int e = 0; e < 8; ++e) {
      float p = (j0 + e <= i) ? __expf(vals[e] - mx) : 0.f;
      vals[e] = p;
      sum += p;
    }
  }
#pragma unroll
  for (int off = 32; off; off >>= 1) sum += __shfl_xor(sum, off);
  __shared__ float reds[4];
  if ((t & 63) == 0) reds[t >> 6] = sum;
  __syncthreads();
  sum = reds[0] + reds[1] + reds[2] + reds[3];
  const float inv = 1.0f / sum;

  if (active) {
    bf16x8 o;
#pragma unroll
    for (int e = 0; e < 8; ++e) o[e] = (bf16_t)(vals[e] * inv);
    ((bf16x8*)row)[t] = o;
  }
}

// ---------------------------------------------------------------------------
// XCD-chunked bijective remap (requires nwg % 8 == 0; all grids comply).
// ---------------------------------------------------------------------------
__device__ __forceinline__ void xcd_remap(int& bx, int& by, int& bz) {
  const int gx = gridDim.x, gy = gridDim.y;
  int lin = (blockIdx.z * gy + blockIdx.y) * gx + blockIdx.x;
  const int nwg = gx * gy * (int)gridDim.z;
  lin = (lin & 7) * (nwg >> 3) + (lin >> 3);
  bx = lin % gx;
  const int rem = lin / gx;
  by = rem % gy;
  bz = rem / gy;
}

// ---------------------------------------------------------------------------
// 128x128 GEMM core, BK=64, two inner k-passes (32 MFMA per barrier pair),
// XOR-swizzled LDS (T2, both-sides): stage slot (c&7)^(row&7) via pre-swizzled
// DMA source; read slot (kp*4+kg)^(row&7).
// ---------------------------------------------------------------------------
__device__ __forceinline__ void gemm_core(char* smem,
                                          const bf16_t* __restrict__ A,
                                          const bf16_t* __restrict__ B,
                                          int K, int KT, int m0, int n0,
                                          f32x4 (&acc)[4][4]) {
  char* const asb = smem;
  char* const bsb = smem + 16384;
  const int t = threadIdx.x;
  const int l = t & 63;
  const int w = t >> 6;
  const int wr = w >> 1, wc = w & 1;
  const int r16 = l & 15, kg = l >> 4;

  const bf16_t* a_src[4];
  const bf16_t* b_src[4];
#pragma unroll
  for (int i = 0; i < 4; ++i) {
    const int c = i * 256 + t;
    const int row = c >> 3;
    const int sl = (c & 7) ^ (row & 7);
    a_src[i] = A + (long)(m0 + row) * K + sl * 8;
    b_src[i] = B + (long)(n0 + row) * K + sl * 8;
  }

  int aoff[2][4], boff[2][4];
#pragma unroll
  for (int kp = 0; kp < 2; ++kp)
#pragma unroll
    for (int mi = 0; mi < 4; ++mi) {
      const int ra = wr * 64 + mi * 16 + r16;
      aoff[kp][mi] = ra * 128 + ((kp * 4 + kg) ^ (ra & 7)) * 16;
      const int rb = wc * 64 + mi * 16 + r16;
      boff[kp][mi] = rb * 128 + ((kp * 4 + kg) ^ (rb & 7)) * 16;
    }

  for (int kt = 0; kt < KT; ++kt) {
    __syncthreads();
#pragma unroll
    for (int i = 0; i < 4; ++i) {
      GLD_LDS16(a_src[i], asb + i * 4096 + w * 1024);
      GLD_LDS16(b_src[i], bsb + i * 4096 + w * 1024);
      a_src[i] += 64;
      b_src[i] += 64;
    }
    __syncthreads();

#pragma unroll
    for (int kp = 0; kp < 2; ++kp) {
      bf16x8 af[4], bfr[4];
#pragma unroll
      for (int mi = 0; mi < 4; ++mi) af[mi] = *(const bf16x8*)(asb + aoff[kp][mi]);
#pragma unroll
      for (int ni = 0; ni < 4; ++ni) bfr[ni] = *(const bf16x8*)(bsb + boff[kp][ni]);
#pragma unroll
      for (int mi = 0; mi < 4; ++mi)
#pragma unroll
        for (int ni = 0; ni < 4; ++ni)
          acc[mi][ni] =
              __builtin_amdgcn_mfma_f32_16x16x32_bf16(af[mi], bfr[ni], acc[mi][ni], 0, 0, 0);
    }
  }
}

// ---------------------------------------------------------------------------
// Generic GEMM kernel: C = alpha*A[M,K]*B[N,K]^T (+bias). EPI 0=fp32, 1=bf16.
// KBOUND: K limited to n0+128 (PV).
// ---------------------------------------------------------------------------
template <int EPI, bool BIAS, bool KBOUND>
__global__ __launch_bounds__(256, 4) void gemm_bt(const bf16_t* __restrict__ Ag,
                                                  const bf16_t* __restrict__ Bg,
                                                  const float* __restrict__ bias,
                                                  void* __restrict__ Cout,
                                                  int N, int K, float alpha,
                                                  long sAb, long sBb, long sCb, int eltC) {
  int bx, by, bz;
  xcd_remap(bx, by, bz);
  const int m0 = by << 7, n0 = bx << 7;

  int KT = K >> 6;
  if (KBOUND) {
    const int kb = (n0 + 128) >> 6;
    if (kb < KT) KT = kb;
  }

  __shared__ __align__(16) char smem[32768];
  f32x4 acc[4][4] = {};
  gemm_core(smem, Ag + (long)bz * sAb, Bg + (long)bz * sBb, K, KT, m0, n0, acc);

  const int t = threadIdx.x;
  const int l = t & 63;
  const int w = t >> 6;
  const int wr = w >> 1, wc = w & 1;
  const int rowbase = m0 + wr * 64 + ((l >> 4) << 2);
  const int colbase = n0 + wc * 64 + (l & 15);
  if constexpr (EPI == 0) {
    float* C = (float*)((char*)Cout + (long)bz * sCb * eltC);
#pragma unroll
    for (int mi = 0; mi < 4; ++mi)
#pragma unroll
      for (int ni = 0; ni < 4; ++ni) {
        const int col = colbase + ni * 16;
        float badd = 0.f;
        if constexpr (BIAS) badd = bias[col];
#pragma unroll
        for (int j = 0; j < 4; ++j)
          C[(long)(rowbase + mi * 16 + j) * N + col] = acc[mi][ni][j] * alpha + badd;
      }
  } else {
    bf16_t* C = (bf16_t*)((char*)Cout + (long)bz * sCb * eltC);
#pragma unroll
    for (int mi = 0; mi < 4; ++mi)
#pragma unroll
      for (int ni = 0; ni < 4; ++ni) {
        const int col = colbase + ni * 16;
        float badd = 0.f;
        if constexpr (BIAS) badd = bias[col];
#pragma unroll
        for (int j = 0; j < 4; ++j)
          C[(long)(rowbase + mi * 16 + j) * N + col] = (bf16_t)(acc[mi][ni][j] * alpha + badd);
      }
  }
}

// ---------------------------------------------------------------------------
// Scores on a triangular-packed grid: exactly 544 blocks (4 batches x 136
// lower-tri 128^2 tiles), no empty blocks. lin -> (z, by, bx) decode is
// wave-uniform scalar. S[z] = qp[z] x kp[z]^T * (1/32).
// ---------------------------------------------------------------------------
__global__ __launch_bounds__(256, 4) void gemm_scores(const bf16_t* __restrict__ qp,
                                                      const bf16_t* __restrict__ kp,
                                                      bf16_t* __restrict__ S,
                                                      long nd, long nn) {
  int bx, by, bz;
  xcd_remap(bx, by, bz);  // grid (544,1,1): by=bz=0, bx = remapped lin
  const int lin = bx;
  const int z = lin / 136;
  const int rem = lin - z * 136;
  int r = (int)((sqrtf(8.0f * rem + 1.0f) - 1.0f) * 0.5f);
  while ((r + 1) * (r + 2) / 2 <= rem) ++r;
  while (r * (r + 1) / 2 > rem) --r;
  const int cx = rem - r * (r + 1) / 2;
  const int m0 = r << 7, n0 = cx << 7;

  __shared__ __align__(16) char smem[32768];
  f32x4 acc[4][4] = {};
  gemm_core(smem, qp + (long)z * nd, kp + (long)z * nd, 1024, 16, m0, n0, acc);

  const int t = threadIdx.x;
  const int l = t & 63;
  const int w = t >> 6;
  const int wr = w >> 1, wc = w & 1;
  const int rowbase = m0 + wr * 64 + ((l >> 4) << 2);
  const int colbase = n0 + wc * 64 + (l & 15);
  bf16_t* C = S + (long)z * nn;
#pragma unroll
  for (int mi = 0; mi < 4; ++mi)
#pragma unroll
    for (int ni = 0; ni < 4; ++ni) {
      const int col = colbase + ni * 16;
#pragma unroll
      for (int j = 0; j < 4; ++j)
        C[(long)(rowbase + mi * 16 + j) * 2048 + col] = (bf16_t)(acc[mi][ni][j] * 0.03125f);
    }
}

// ---------------------------------------------------------------------------
// Fused QKV projections. z<2: qp/kp normal store. z==2: V-projection output is
// transposed into vpT[b][d][n] via a chunk-XOR-swizzled LDS transpose.
// ---------------------------------------------------------------------------
struct Qkv3Args {
  const bf16_t* A[3];
  const bf16_t* W[3];
  const float* bias[3];
  bf16_t* C[3];
};

__global__ __launch_bounds__(256, 4) void qkv3(Qkv3Args ga, int N, int K) {
  int bx, by, bz;
  xcd_remap(bx, by, bz);
  const int m0 = by << 7, n0 = bx << 7;

  __shared__ __align__(16) char smem[32768];
  f32x4 acc[4][4] = {};
  gemm_core(smem, ga.A[bz], ga.W[bz], K, K >> 6, m0, n0, acc);

  const float* __restrict__ bias = ga.bias[bz];
  const int t = threadIdx.x;
  const int l = t & 63;
  const int w = t >> 6;
  const int wr = w >> 1, wc = w & 1;
  const int r16 = l & 15, kg = l >> 4;

  if (bz < 2) {
    bf16_t* C = ga.C[bz];  // [8192,1024]
    const int rowbase = m0 + wr * 64 + kg * 4;
    const int colbase = n0 + wc * 64 + r16;
#pragma unroll
    for (int mi = 0; mi < 4; ++mi)
#pragma unroll
      for (int ni = 0; ni < 4; ++ni) {
        const int col = colbase + ni * 16;
        const float badd = bias[col];
#pragma unroll
        for (int j = 0; j < 4; ++j)
          C[(long)(rowbase + mi * 16 + j) * N + col] = (bf16_t)(acc[mi][ni][j] + badd);
      }
  } else {
    // transpose in LDS (chunk-XOR swizzled), then coalesced 16B stores along n
    __syncthreads();  // K-loop LDS reads complete before overwrite
    char* tt = smem;  // [128 rows(d)][256 B], phys chunk = logical^(lc&7)
#pragma unroll
    for (int mi = 0; mi < 4; ++mi)
#pragma unroll
      for (int ni = 0; ni < 4; ++ni) {
        const int lc = wc * 64 + ni * 16 + r16;            // local d-col
        const int lrb = (wr * 64 + mi * 16 + kg * 4) * 2;  // local n-row byte
        const float badd = bias[n0 + lc];
        bf16x4 o;
#pragma unroll
        for (int j = 0; j < 4; ++j) o[j] = (bf16_t)(acc[mi][ni][j] + badd);
        *(bf16x4*)(tt + lc * 256 + (lrb ^ ((lc & 7) << 4))) = o;
      }
    __syncthreads();
    bf16_t* C = ga.C[2];  // vpT: per-batch [1024][2048]
    const int batch = m0 >> 11, nb = m0 & 2047;
#pragma unroll
    for (int i = 0; i < 8; ++i) {
      const int c = i * 256 + t;
      const int lc = c >> 4, ch = c & 15;
      *(bf16x8*)(C + (long)batch * (2048 * 1024) + (long)(n0 + lc) * 2048 + nb + ch * 8) =
          *(const bf16x8*)(tt + lc * 256 + ((ch * 16) ^ ((lc & 7) << 4)));
    }
  }
}

// ---------------------------------------------------------------------------
extern "C" void kernel_launch(void* const* d_in, const int* in_sizes, int n_in,
                              void* d_out, int out_size, void* d_ws, size_t ws_size,
                              hipStream_t stream) {
  const int b = 4, n = 2048, d = 1024;
  const long nd  = (long)n * d;
  const long bn  = (long)b * n;
  const long bnd = bn * d;
  const long ddl = (long)d * d;
  const long nn  = (long)n * n;

  const float* q  = (const float*)d_in[0];
  const float* k  = (const float*)d_in[1];
  const float* v  = (const float*)d_in[2];
  const float* Wq = (const float*)d_in[3];
  const float* bq = (const float*)d_in[4];
  const float* Wk = (const float*)d_in[5];
  const float* bk = (const float*)d_in[6];
  const float* Wv = (const float*)d_in[7];
  const float* bv = (const float*)d_in[8];
  const float* Wo = (const float*)d_in[9];
  const float* bo = (const float*)d_in[10];

  bf16_t* ws  = (bf16_t*)d_ws;
  bf16_t* qB  = ws;              // bnd
  bf16_t* kB  = qB + bnd;        // bnd
  bf16_t* vB  = kB + bnd;        // bnd
  bf16_t* WqB = vB + bnd;        // ddl x4
  bf16_t* WkB = WqB + ddl;
  bf16_t* WvB = WkB + ddl;
  bf16_t* WoB = WvB + ddl;
  bf16_t* qpB = WoB + ddl;       // bnd
  bf16_t* kpB = qpB + bnd;       // bnd
  bf16_t* vpT = kpB + bnd;       // bnd (per-batch [d][n], from qkv3 epilogue)
  bf16_t* S   = vpT + bnd;       // b*nn
  bf16_t* yT  = S + (long)b * nn;// bnd
  const size_t need = (size_t)(7 * bnd + 4 * ddl + (long)b * nn) * 2;
  if (ws_size < need) return;

  dim3 blk(256);

  // fp32 -> bf16 converts: ONE launch, 7 segments, 32 B/lane
  CvtArgs ca;
  ca.src[0] = q;  ca.dst[0] = qB;  ca.n4[0] = bnd / 4;
  ca.src[1] = k;  ca.dst[1] = kB;  ca.n4[1] = bnd / 4;
  ca.src[2] = v;  ca.dst[2] = vB;  ca.n4[2] = bnd / 4;
  ca.src[3] = Wq; ca.dst[3] = WqB; ca.n4[3] = ddl / 4;
  ca.src[4] = Wk; ca.dst[4] = WkB; ca.n4[4] = ddl / 4;
  ca.src[5] = Wv; ca.dst[5] = WvB; ca.n4[5] = ddl / 4;
  ca.src[6] = Wo; ca.dst[6] = WoB; ca.n4[6] = ddl / 4;
  cvt_all<<<dim3(512, 7), blk, 0, stream>>>(ca);

  // fused QKV projections (BK=64 core): grid (8, 64, 3) = 1536 blocks
  Qkv3Args qa;
  qa.A[0] = qB; qa.W[0] = WqB; qa.bias[0] = bq; qa.C[0] = qpB;
  qa.A[1] = kB; qa.W[1] = WkB; qa.bias[1] = bk; qa.C[1] = kpB;
  qa.A[2] = vB; qa.W[2] = WvB; qa.bias[2] = bv; qa.C[2] = vpT;
  qkv3<<<dim3(d / 128, bn / 128, 3), blk, 0, stream>>>(qa, d, d);

  // scores: triangular-packed grid, 544 blocks (no empty blocks)
  gemm_scores<<<dim3(544, 1, 1), blk, 0, stream>>>(qpB, kpB, S, nd, nn);

  // causal softmax in place (bounded to the straddle tile)
  softmax_causal<<<dim3(n, b), blk, 0, stream>>>(S, n, nn);

  // yT[z] = vpT[z] x P[z]^T   (K bounded per N-tile by causality)
  gemm_bt<1, false, true><<<dim3(n / 128, d / 128, b), blk, 0, stream>>>(
      vpT, S, nullptr, yT, n, n, 1.f, nd, nn, nd, 2);

  // out = y2 x Wo^T + bo ; y2 flat == yT flat, fp32 out
  gemm_bt<0, true, false><<<dim3(d / 128, bn / 128, 1), blk, 0, stream>>>(
      yT, WoB, bo, (float*)d_out, d, d, 1.f, 0, 0, 0, 4);
}

// Round 13
// 182.415 us; speedup vs baseline: 1.0691x; 1.0691x over previous
//
#include <hip/hip_runtime.h>
#include <hip/hip_bf16.h>
#include <stdint.h>

typedef __bf16 bf16_t;
typedef __bf16 bf16x8 __attribute__((ext_vector_type(8)));
typedef __bf16 bf16x4 __attribute__((ext_vector_type(4)));
typedef float f32x4 __attribute__((ext_vector_type(4)));

#define GLD_LDS16(src, dst)                                                              \
  __builtin_amdgcn_global_load_lds((const __attribute__((address_space(1))) void*)(src), \
                                   (__attribute__((address_space(3))) void*)(dst), 16, 0, 0)

#define BAR() __builtin_amdgcn_s_barrier()
#define LGKM0() asm volatile("s_waitcnt lgkmcnt(0)" ::: "memory")
#define VMCN(n) asm volatile("s_waitcnt vmcnt(" #n ")" ::: "memory")
#define SCH0() __builtin_amdgcn_sched_barrier(0)

__device__ __forceinline__ int swz(int x) { return x ^ (((x >> 9) & 1) << 5); }

// ---------------------------------------------------------------------------
// fp32 -> bf16 convert (R11-proven form: 16B load / 8B store per lane).
// ---------------------------------------------------------------------------
struct CvtArgs {
  const float* src[7];
  bf16_t* dst[7];
  long n4[7];
};

__global__ __launch_bounds__(256) void cvt_all(CvtArgs a) {
  const int seg = blockIdx.y;
  const float* __restrict__ in = a.src[seg];
  bf16_t* __restrict__ out = a.dst[seg];
  const long n4 = a.n4[seg];
  long i = (long)blockIdx.x * blockDim.x + threadIdx.x;
  const long stride = (long)gridDim.x * blockDim.x;
  for (; i < n4; i += stride) {
    float4 v = ((const float4*)in)[i];
    bf16x4 o;
    o[0] = (bf16_t)v.x; o[1] = (bf16_t)v.y; o[2] = (bf16_t)v.z; o[3] = (bf16_t)v.w;
    ((bf16x4*)out)[i] = o;
  }
}

// ---------------------------------------------------------------------------
// Causal row softmax, in-place, bounded to j < (floor(i/128)+1)*128.
// ---------------------------------------------------------------------------
__global__ __launch_bounds__(256) void softmax_causal(bf16_t* __restrict__ S, int n, long sB) {
  const int i = blockIdx.x;
  const int z = blockIdx.y;
  bf16_t* row = S + (long)z * sB + (long)i * n;
  const int t = threadIdx.x;
  const int j0 = t << 3;
  const int jmax = ((i >> 7) + 1) << 7;
  const bool active = j0 < jmax;

  float vals[8];
  float mx = -3.0e38f;
  if (active) {
    bf16x8 vv = ((const bf16x8*)row)[t];
#pragma unroll
    for (int e = 0; e < 8; ++e) {
      float v = (j0 + e <= i) ? (float)vv[e] : -3.0e38f;
      vals[e] = v;
      mx = fmaxf(mx, v);
    }
  }
#pragma unroll
  for (int off = 32; off; off >>= 1) mx = fmaxf(mx, __shfl_xor(mx, off));
  __shared__ float redm[4];
  if ((t & 63) == 0) redm[t >> 6] = mx;
  __syncthreads();
  mx = fmaxf(fmaxf(redm[0], redm[1]), fmaxf(redm[2], redm[3]));

  float sum = 0.f;
  if (active) {
#pragma unroll
    for (int e = 0; e < 8; ++e) {
      float p = (j0 + e <= i) ? __expf(vals[e] - mx) : 0.f;
      vals[e] = p;
      sum += p;
    }
  }
#pragma unroll
  for (int off = 32; off; off >>= 1) sum += __shfl_xor(sum, off);
  __shared__ float reds[4];
  if ((t & 63) == 0) reds[t >> 6] = sum;
  __syncthreads();
  sum = reds[0] + reds[1] + reds[2] + reds[3];
  const float inv = 1.0f / sum;

  if (active) {
    bf16x8 o;
#pragma unroll
    for (int e = 0; e < 8; ++e) o[e] = (bf16_t)(vals[e] * inv);
    ((bf16x8*)row)[t] = o;
  }
}

// ---------------------------------------------------------------------------
// XCD-chunked bijective remap (requires nwg % 8 == 0; all grids comply).
// ---------------------------------------------------------------------------
__device__ __forceinline__ void xcd_remap(int& bx, int& by, int& bz) {
  const int gx = gridDim.x, gy = gridDim.y;
  int lin = (blockIdx.z * gy + blockIdx.y) * gx + blockIdx.x;
  const int nwg = gx * gy * (int)gridDim.z;
  lin = (lin & 7) * (nwg >> 3) + (lin >> 3);
  bx = lin % gx;
  const int rem = lin / gx;
  by = rem % gy;
  bz = rem / gy;
}

// ---------------------------------------------------------------------------
// 128x128 GEMM core, BK=64, XOR-swizzled LDS (R10/R11-proven).
// ---------------------------------------------------------------------------
__device__ __forceinline__ void gemm_core(char* smem,
                                          const bf16_t* __restrict__ A,
                                          const bf16_t* __restrict__ B,
                                          int K, int KT, int m0, int n0,
                                          f32x4 (&acc)[4][4]) {
  char* const asb = smem;
  char* const bsb = smem + 16384;
  const int t = threadIdx.x;
  const int l = t & 63;
  const int w = t >> 6;
  const int wr = w >> 1, wc = w & 1;
  const int r16 = l & 15, kg = l >> 4;

  const bf16_t* a_src[4];
  const bf16_t* b_src[4];
#pragma unroll
  for (int i = 0; i < 4; ++i) {
    const int c = i * 256 + t;
    const int row = c >> 3;
    const int sl = (c & 7) ^ (row & 7);
    a_src[i] = A + (long)(m0 + row) * K + sl * 8;
    b_src[i] = B + (long)(n0 + row) * K + sl * 8;
  }

  int aoff[2][4], boff[2][4];
#pragma unroll
  for (int kp = 0; kp < 2; ++kp)
#pragma unroll
    for (int mi = 0; mi < 4; ++mi) {
      const int ra = wr * 64 + mi * 16 + r16;
      aoff[kp][mi] = ra * 128 + ((kp * 4 + kg) ^ (ra & 7)) * 16;
      const int rb = wc * 64 + mi * 16 + r16;
      boff[kp][mi] = rb * 128 + ((kp * 4 + kg) ^ (rb & 7)) * 16;
    }

  for (int kt = 0; kt < KT; ++kt) {
    __syncthreads();
#pragma unroll
    for (int i = 0; i < 4; ++i) {
      GLD_LDS16(a_src[i], asb + i * 4096 + w * 1024);
      GLD_LDS16(b_src[i], bsb + i * 4096 + w * 1024);
      a_src[i] += 64;
      b_src[i] += 64;
    }
    __syncthreads();

#pragma unroll
    for (int kp = 0; kp < 2; ++kp) {
      bf16x8 af[4], bfr[4];
#pragma unroll
      for (int mi = 0; mi < 4; ++mi) af[mi] = *(const bf16x8*)(asb + aoff[kp][mi]);
#pragma unroll
      for (int ni = 0; ni < 4; ++ni) bfr[ni] = *(const bf16x8*)(bsb + boff[kp][ni]);
#pragma unroll
      for (int mi = 0; mi < 4; ++mi)
#pragma unroll
        for (int ni = 0; ni < 4; ++ni)
          acc[mi][ni] =
              __builtin_amdgcn_mfma_f32_16x16x32_bf16(af[mi], bfr[ni], acc[mi][ni], 0, 0, 0);
    }
  }
}

// ---------------------------------------------------------------------------
// Generic GEMM kernel (PV / out-proj). EPI 0=fp32, 1=bf16. KBOUND for PV.
// ---------------------------------------------------------------------------
template <int EPI, bool BIAS, bool KBOUND>
__global__ __launch_bounds__(256, 4) void gemm_bt(const bf16_t* __restrict__ Ag,
                                                  const bf16_t* __restrict__ Bg,
                                                  const float* __restrict__ bias,
                                                  void* __restrict__ Cout,
                                                  int N, int K, float alpha,
                                                  long sAb, long sBb, long sCb, int eltC) {
  int bx, by, bz;
  xcd_remap(bx, by, bz);
  const int m0 = by << 7, n0 = bx << 7;

  int KT = K >> 6;
  if (KBOUND) {
    const int kb = (n0 + 128) >> 6;
    if (kb < KT) KT = kb;
  }

  __shared__ __align__(16) char smem[32768];
  f32x4 acc[4][4] = {};
  gemm_core(smem, Ag + (long)bz * sAb, Bg + (long)bz * sBb, K, KT, m0, n0, acc);

  const int t = threadIdx.x;
  const int l = t & 63;
  const int w = t >> 6;
  const int wr = w >> 1, wc = w & 1;
  const int rowbase = m0 + wr * 64 + ((l >> 4) << 2);
  const int colbase = n0 + wc * 64 + (l & 15);
  if constexpr (EPI == 0) {
    float* C = (float*)((char*)Cout + (long)bz * sCb * eltC);
#pragma unroll
    for (int mi = 0; mi < 4; ++mi)
#pragma unroll
      for (int ni = 0; ni < 4; ++ni) {
        const int col = colbase + ni * 16;
        float badd = 0.f;
        if constexpr (BIAS) badd = bias[col];
#pragma unroll
        for (int j = 0; j < 4; ++j)
          C[(long)(rowbase + mi * 16 + j) * N + col] = acc[mi][ni][j] * alpha + badd;
      }
  } else {
    bf16_t* C = (bf16_t*)((char*)Cout + (long)bz * sCb * eltC);
#pragma unroll
    for (int mi = 0; mi < 4; ++mi)
#pragma unroll
      for (int ni = 0; ni < 4; ++ni) {
        const int col = colbase + ni * 16;
        float badd = 0.f;
        if constexpr (BIAS) badd = bias[col];
#pragma unroll
        for (int j = 0; j < 4; ++j)
          C[(long)(rowbase + mi * 16 + j) * N + col] = (bf16_t)(acc[mi][ni][j] * alpha + badd);
      }
  }
}

// ---------------------------------------------------------------------------
// Fused QKV projections (R11-proven). z<2: normal store; z==2: V transposed
// into vpT via chunk-XOR-swizzled LDS transpose.
// ---------------------------------------------------------------------------
struct Qkv3Args {
  const bf16_t* A[3];
  const bf16_t* W[3];
  const float* bias[3];
  bf16_t* C[3];
};

__global__ __launch_bounds__(256, 4) void qkv3(Qkv3Args ga, int N, int K) {
  int bx, by, bz;
  xcd_remap(bx, by, bz);
  const int m0 = by << 7, n0 = bx << 7;

  __shared__ __align__(16) char smem[32768];
  f32x4 acc[4][4] = {};
  gemm_core(smem, ga.A[bz], ga.W[bz], K, K >> 6, m0, n0, acc);

  const float* __restrict__ bias = ga.bias[bz];
  const int t = threadIdx.x;
  const int l = t & 63;
  const int w = t >> 6;
  const int wr = w >> 1, wc = w & 1;
  const int r16 = l & 15, kg = l >> 4;

  if (bz < 2) {
    bf16_t* C = ga.C[bz];
    const int rowbase = m0 + wr * 64 + kg * 4;
    const int colbase = n0 + wc * 64 + r16;
#pragma unroll
    for (int mi = 0; mi < 4; ++mi)
#pragma unroll
      for (int ni = 0; ni < 4; ++ni) {
        const int col = colbase + ni * 16;
        const float badd = bias[col];
#pragma unroll
        for (int j = 0; j < 4; ++j)
          C[(long)(rowbase + mi * 16 + j) * N + col] = (bf16_t)(acc[mi][ni][j] + badd);
      }
  } else {
    __syncthreads();
    char* tt = smem;  // [128 rows(d)][256 B], phys chunk = logical^(lc&7)
#pragma unroll
    for (int mi = 0; mi < 4; ++mi)
#pragma unroll
      for (int ni = 0; ni < 4; ++ni) {
        const int lc = wc * 64 + ni * 16 + r16;
        const int lrb = (wr * 64 + mi * 16 + kg * 4) * 2;
        const float badd = bias[n0 + lc];
        bf16x4 o;
#pragma unroll
        for (int j = 0; j < 4; ++j) o[j] = (bf16_t)(acc[mi][ni][j] + badd);
        *(bf16x4*)(tt + lc * 256 + (lrb ^ ((lc & 7) << 4))) = o;
      }
    __syncthreads();
    bf16_t* C = ga.C[2];
    const int batch = m0 >> 11, nb = m0 & 2047;
#pragma unroll
    for (int i = 0; i < 8; ++i) {
      const int c = i * 256 + t;
      const int lc = c >> 4, ch = c & 15;
      *(bf16x8*)(C + (long)batch * (2048 * 1024) + (long)(n0 + lc) * 2048 + nb + ch * 8) =
          *(const bf16x8*)(tt + lc * 256 + ((ch * 16) ^ ((lc & 7) << 4)));
    }
  }
}

// ===========================================================================
// Faithful m201 8-phase 256x256 GEMM — scores only.
// Phase = {ds_read THIS phase's frags; stage 1 half-tile; BAR; lgkmcnt(0);
// setprio(1) 16 MFMA setprio(0); BAR}. vmcnt(6) at P4/P8 ONLY (ledger:
// outstanding 14 -> complete 8 = exactly next tile's 4 half-tiles).
// Quadrant order Q00,Q01,Q11,Q10 so P4/P8 read nothing.
// ===========================================================================
template <int HALF, int BUF>
__device__ __forceinline__ void stage8(char* lds, const bf16_t* srcH, const int (&soff)[2],
                                       int wid, int tile) {
  const bf16_t* s = srcH + tile * 64;
  char* d = lds + (HALF >= 2 ? 65536 : 0) + BUF * 32768 + (HALF & 1) * 16384 + wid * 2048;
  GLD_LDS16(s + soff[0], d);
  GLD_LDS16(s + soff[1], d + 1024);
}

template <int BUF, int QM>
__device__ __forceinline__ void rdA(char* lds, const int (&aoffp)[4][2], bf16x8 (&af)[4][2]) {
  char* b = lds + BUF * 32768 + QM * 16384;
#pragma unroll
  for (int mi = 0; mi < 4; ++mi)
#pragma unroll
    for (int kk = 0; kk < 2; ++kk) af[mi][kk] = *(const bf16x8*)(b + aoffp[mi][kk]);
}

template <int BUF, int QN>
__device__ __forceinline__ void rdB(char* lds, const int (&boffp)[2][2], bf16x8 (&bf)[2][2]) {
  char* b = lds + 65536 + BUF * 32768 + QN * 16384;
#pragma unroll
  for (int ni = 0; ni < 2; ++ni)
#pragma unroll
    for (int kk = 0; kk < 2; ++kk) bf[ni][kk] = *(const bf16x8*)(b + boffp[ni][kk]);
}

template <int QM, int QN>
__device__ __forceinline__ void mm16(f32x4 (&acc)[2][2][4][2], const bf16x8 (&af)[4][2],
                                     const bf16x8 (&bf)[2][2]) {
  __builtin_amdgcn_s_setprio(1);
#pragma unroll
  for (int mi = 0; mi < 4; ++mi)
#pragma unroll
    for (int ni = 0; ni < 2; ++ni)
#pragma unroll
      for (int kk = 0; kk < 2; ++kk)
        acc[QM][QN][mi][ni] = __builtin_amdgcn_mfma_f32_16x16x32_bf16(
            af[mi][kk], bf[ni][kk], acc[QM][QN][mi][ni], 0, 0, 0);
  __builtin_amdgcn_s_setprio(0);
}

template <bool LAST>
__device__ __forceinline__ void kiter8(char* lds, int tt,
    const bf16_t* srcA0, const bf16_t* srcA1, const bf16_t* srcB0, const bf16_t* srcB1,
    const int (&soff)[2], int wid,
    const int (&aoffp)[4][2], const int (&boffp)[2][2],
    bf16x8 (&af)[4][2], bf16x8 (&bf0)[2][2], bf16x8 (&bf1)[2][2],
    f32x4 (&acc)[2][2][4][2]) {
  // P1: Q00(t,b0). reads A0,B0(b0). stage A1(t+1)->b1 (A1(b1) last read prev P7).
  rdA<0, 0>(lds, aoffp, af);
  rdB<0, 0>(lds, boffp, bf0);
  stage8<1, 1>(lds, srcA1, soff, wid, tt + 1);
  BAR(); LGKM0(); SCH0();
  mm16<0, 0>(acc, af, bf0);
  BAR();
  // P2: Q01(t). reads B1(b0). stage A0(t+2)->b0 (A0(b0) last read P1).
  rdB<0, 1>(lds, boffp, bf1);
  if (!LAST) stage8<0, 0>(lds, srcA0, soff, wid, tt + 2);
  BAR(); LGKM0(); SCH0();
  mm16<0, 1>(acc, af, bf1);
  BAR();
  // P3: Q11(t). reads A1(b0). stage B0(t+2)->b0 (B0(b0) last read P1).
  rdA<0, 1>(lds, aoffp, af);
  if (!LAST) stage8<2, 0>(lds, srcB0, soff, wid, tt + 2);
  BAR(); LGKM0(); SCH0();
  mm16<1, 1>(acc, af, bf1);
  BAR();
  // P4: Q10(t) (af=A1, bf0=B0 live; no reads). stage B1(t+2)->b0 (read P2).
  if (!LAST) stage8<3, 0>(lds, srcB1, soff, wid, tt + 2);
  BAR(); LGKM0(); SCH0();
  mm16<1, 0>(acc, af, bf0);
  BAR();
  // K-tile boundary: secure tile t+1 (completes its 4 half-tiles; 6 remain in flight).
  if (LAST) { VMCN(0); } else { VMCN(6); }
  // P5: Q00(t+1,b1). reads A0,B0(b1). stage A1(t+2)->b0 (A1(b0) last read P3).
  rdA<1, 0>(lds, aoffp, af);
  rdB<1, 0>(lds, boffp, bf0);
  if (!LAST) stage8<1, 0>(lds, srcA1, soff, wid, tt + 2);
  BAR(); LGKM0(); SCH0();
  mm16<0, 0>(acc, af, bf0);
  BAR();
  // P6: Q01(t+1). reads B1(b1). stage A0(t+3)->b1 (A0(b1) last read P5).
  rdB<1, 1>(lds, boffp, bf1);
  if (!LAST) stage8<0, 1>(lds, srcA0, soff, wid, tt + 3);
  BAR(); LGKM0(); SCH0();
  mm16<0, 1>(acc, af, bf1);
  BAR();
  // P7: Q11(t+1). reads A1(b1). stage B0(t+3)->b1 (B0(b1) last read P5).
  rdA<1, 1>(lds, aoffp, af);
  if (!LAST) stage8<2, 1>(lds, srcB0, soff, wid, tt + 3);
  BAR(); LGKM0(); SCH0();
  mm16<1, 1>(acc, af, bf1);
  BAR();
  // P8: Q10(t+1) (no reads). stage B1(t+3)->b1 (B1(b1) last read P6).
  if (!LAST) stage8<3, 1>(lds, srcB1, soff, wid, tt + 3);
  BAR(); LGKM0(); SCH0();
  mm16<1, 0>(acc, af, bf0);
  BAR();
  // K-tile boundary: secure tile t+2 before next-iter P1 reads b0.
  if (!LAST) { VMCN(6); }
}

__global__ __launch_bounds__(512, 1) void gemm8_scores(const bf16_t* __restrict__ qp,
                                                       const bf16_t* __restrict__ kp,
                                                       bf16_t* __restrict__ S,
                                                       long nd, long nn) {
  int bx, by, bz;
  xcd_remap(bx, by, bz);  // grid (8,8,4) = 256 blocks, nwg%8==0
  const int m0 = by << 8, n0 = bx << 8;
  if (n0 > m0 + 255) return;  // causal tile skip (uniform, pre-barrier)

  const int K = 1024, NT = 16;
  const bf16_t* A = qp + (long)bz * nd;
  const bf16_t* B = kp + (long)bz * nd;

  __shared__ __align__(16) char lds[131072];

  const int t = threadIdx.x;
  const int wid = t >> 6, l = t & 63;
  const int wm = wid >> 2, wn = wid & 3;
  const int ri16 = l & 15, kg = l >> 4;

  int soff[2];
#pragma unroll
  for (int i = 0; i < 2; ++i) {
    const int sub = wid * 2 + i;
    const int ri = l >> 2;
    const int cq = (l & 3) ^ ((ri & 8) >> 2);
    const int r = (sub >> 1) * 16 + ri;
    const int c = (sub & 1) * 32 + cq * 8;
    soff[i] = r * K + c;
  }
  const bf16_t* srcA0 = A + (long)m0 * K;
  const bf16_t* srcA1 = A + (long)(m0 + 128) * K;
  const bf16_t* srcB0 = B + (long)n0 * K;
  const bf16_t* srcB1 = B + (long)(n0 + 128) * K;

  int aoffp[4][2], boffp[2][2];
#pragma unroll
  for (int mi = 0; mi < 4; ++mi)
#pragma unroll
    for (int kk = 0; kk < 2; ++kk)
      aoffp[mi][kk] = swz((wm * 4 + mi) * 2048 + kk * 1024 + ri16 * 64 + kg * 16);
#pragma unroll
  for (int ni = 0; ni < 2; ++ni)
#pragma unroll
    for (int kk = 0; kk < 2; ++kk)
      boffp[ni][kk] = swz((wn * 2 + ni) * 2048 + kk * 1024 + ri16 * 64 + kg * 16);

  f32x4 acc[2][2][4][2] = {};
  bf16x8 af[4][2], bf0[2][2], bf1[2][2];

  // prologue: t0 fully (8 loads) + t1 {A0,B0,B1} (6 loads); vmcnt(6) -> t0 landed.
  stage8<0, 0>(lds, srcA0, soff, wid, 0);
  stage8<2, 0>(lds, srcB0, soff, wid, 0);
  stage8<3, 0>(lds, srcB1, soff, wid, 0);
  stage8<1, 0>(lds, srcA1, soff, wid, 0);
  stage8<0, 1>(lds, srcA0, soff, wid, 1);
  stage8<2, 1>(lds, srcB0, soff, wid, 1);
  stage8<3, 1>(lds, srcB1, soff, wid, 1);
  VMCN(6);
  BAR();

  for (int tt = 0; tt + 2 < NT; tt += 2)
    kiter8<false>(lds, tt, srcA0, srcA1, srcB0, srcB1, soff, wid, aoffp, boffp,
                  af, bf0, bf1, acc);
  kiter8<true>(lds, NT - 2, srcA0, srcA1, srcB0, srcB1, soff, wid, aoffp, boffp,
               af, bf0, bf1, acc);

  bf16_t* C = S + (long)bz * nn;  // [2048][2048]
#pragma unroll
  for (int qm = 0; qm < 2; ++qm)
#pragma unroll
    for (int qn = 0; qn < 2; ++qn)
#pragma unroll
      for (int mi = 0; mi < 4; ++mi)
#pragma unroll
        for (int ni = 0; ni < 2; ++ni) {
          const int col = n0 + qn * 128 + wn * 32 + ni * 16 + ri16;
          const int row0 = m0 + qm * 128 + wm * 64 + mi * 16 + kg * 4;
#pragma unroll
          for (int j = 0; j < 4; ++j)
            C[(long)(row0 + j) * 2048 + col] = (bf16_t)(acc[qm][qn][mi][ni][j] * 0.03125f);
        }
}

// ---------------------------------------------------------------------------
extern "C" void kernel_launch(void* const* d_in, const int* in_sizes, int n_in,
                              void* d_out, int out_size, void* d_ws, size_t ws_size,
                              hipStream_t stream) {
  const int b = 4, n = 2048, d = 1024;
  const long nd  = (long)n * d;
  const long bn  = (long)b * n;
  const long bnd = bn * d;
  const long ddl = (long)d * d;
  const long nn  = (long)n * n;

  const float* q  = (const float*)d_in[0];
  const float* k  = (const float*)d_in[1];
  const float* v  = (const float*)d_in[2];
  const float* Wq = (const float*)d_in[3];
  const float* bq = (const float*)d_in[4];
  const float* Wk = (const float*)d_in[5];
  const float* bk = (const float*)d_in[6];
  const float* Wv = (const float*)d_in[7];
  const float* bv = (const float*)d_in[8];
  const float* Wo = (const float*)d_in[9];
  const float* bo = (const float*)d_in[10];

  bf16_t* ws  = (bf16_t*)d_ws;
  bf16_t* qB  = ws;
  bf16_t* kB  = qB + bnd;
  bf16_t* vB  = kB + bnd;
  bf16_t* WqB = vB + bnd;
  bf16_t* WkB = WqB + ddl;
  bf16_t* WvB = WkB + ddl;
  bf16_t* WoB = WvB + ddl;
  bf16_t* qpB = WoB + ddl;
  bf16_t* kpB = qpB + bnd;
  bf16_t* vpT = kpB + bnd;
  bf16_t* S   = vpT + bnd;
  bf16_t* yT  = S + (long)b * nn;
  const size_t need = (size_t)(7 * bnd + 4 * ddl + (long)b * nn) * 2;
  if (ws_size < need) return;

  dim3 blk(256);

  // fp32 -> bf16 converts (R11 form)
  CvtArgs ca;
  ca.src[0] = q;  ca.dst[0] = qB;  ca.n4[0] = bnd / 4;
  ca.src[1] = k;  ca.dst[1] = kB;  ca.n4[1] = bnd / 4;
  ca.src[2] = v;  ca.dst[2] = vB;  ca.n4[2] = bnd / 4;
  ca.src[3] = Wq; ca.dst[3] = WqB; ca.n4[3] = ddl / 4;
  ca.src[4] = Wk; ca.dst[4] = WkB; ca.n4[4] = ddl / 4;
  ca.src[5] = Wv; ca.dst[5] = WvB; ca.n4[5] = ddl / 4;
  ca.src[6] = Wo; ca.dst[6] = WoB; ca.n4[6] = ddl / 4;
  cvt_all<<<dim3(512, 7), blk, 0, stream>>>(ca);

  // fused QKV projections (R11-proven): grid (8, 64, 3) = 1536 blocks
  Qkv3Args qa;
  qa.A[0] = qB; qa.W[0] = WqB; qa.bias[0] = bq; qa.C[0] = qpB;
  qa.A[1] = kB; qa.W[1] = WkB; qa.bias[1] = bk; qa.C[1] = kpB;
  qa.A[2] = vB; qa.W[2] = WvB; qa.bias[2] = bv; qa.C[2] = vpT;
  qkv3<<<dim3(d / 128, bn / 128, 3), blk, 0, stream>>>(qa, d, d);

  // scores: faithful 8-phase 256^2, grid (8,8,4) = 256 blocks (144 active)
  gemm8_scores<<<dim3(n / 256, n / 256, b), dim3(512), 0, stream>>>(qpB, kpB, S, nd, nn);

  // causal softmax in place (bounded)
  softmax_causal<<<dim3(n, b), blk, 0, stream>>>(S, n, nn);

  // yT[z] = vpT[z] x P[z]^T   (K bounded per N-tile by causality)
  gemm_bt<1, false, true><<<dim3(n / 128, d / 128, b), blk, 0, stream>>>(
      vpT, S, nullptr, yT, n, n, 1.f, nd, nn, nd, 2);

  // out = y2 x Wo^T + bo ; y2 flat == yT flat, fp32 out
  gemm_bt<0, true, false><<<dim3(d / 128, bn / 128, 1), blk, 0, stream>>>(
      yT, WoB, bo, (float*)d_out, d, d, 1.f, 0, 0, 0, 4);
}

// Round 14
// 181.277 us; speedup vs baseline: 1.0758x; 1.0063x over previous
//
#include <hip/hip_runtime.h>
#include <hip/hip_bf16.h>
#include <stdint.h>

typedef __bf16 bf16_t;
typedef __bf16 bf16x8 __attribute__((ext_vector_type(8)));
typedef __bf16 bf16x4 __attribute__((ext_vector_type(4)));
typedef float f32x4 __attribute__((ext_vector_type(4)));

#define GLD_LDS16(src, dst)                                                              \
  __builtin_amdgcn_global_load_lds((const __attribute__((address_space(1))) void*)(src), \
                                   (__attribute__((address_space(3))) void*)(dst), 16, 0, 0)

// ---------------------------------------------------------------------------
// fp32 -> bf16 convert (16B load / 8B store per lane; R11-proven).
// ---------------------------------------------------------------------------
struct CvtArgs {
  const float* src[7];
  bf16_t* dst[7];
  long n4[7];
};

__global__ __launch_bounds__(256) void cvt_all(CvtArgs a) {
  const int seg = blockIdx.y;
  const float* __restrict__ in = a.src[seg];
  bf16_t* __restrict__ out = a.dst[seg];
  const long n4 = a.n4[seg];
  long i = (long)blockIdx.x * blockDim.x + threadIdx.x;
  const long stride = (long)gridDim.x * blockDim.x;
  for (; i < n4; i += stride) {
    float4 v = ((const float4*)in)[i];
    bf16x4 o;
    o[0] = (bf16_t)v.x; o[1] = (bf16_t)v.y; o[2] = (bf16_t)v.z; o[3] = (bf16_t)v.w;
    ((bf16x4*)out)[i] = o;
  }
}

// ---------------------------------------------------------------------------
// Causal row softmax, in-place, bounded to j < (floor(i/128)+1)*128.
// ---------------------------------------------------------------------------
__global__ __launch_bounds__(256) void softmax_causal(bf16_t* __restrict__ S, int n, long sB) {
  const int i = blockIdx.x;
  const int z = blockIdx.y;
  bf16_t* row = S + (long)z * sB + (long)i * n;
  const int t = threadIdx.x;
  const int j0 = t << 3;
  const int jmax = ((i >> 7) + 1) << 7;
  const bool active = j0 < jmax;

  float vals[8];
  float mx = -3.0e38f;
  if (active) {
    bf16x8 vv = ((const bf16x8*)row)[t];
#pragma unroll
    for (int e = 0; e < 8; ++e) {
      float v = (j0 + e <= i) ? (float)vv[e] : -3.0e38f;
      vals[e] = v;
      mx = fmaxf(mx, v);
    }
  }
#pragma unroll
  for (int off = 32; off; off >>= 1) mx = fmaxf(mx, __shfl_xor(mx, off));
  __shared__ float redm[4];
  if ((t & 63) == 0) redm[t >> 6] = mx;
  __syncthreads();
  mx = fmaxf(fmaxf(redm[0], redm[1]), fmaxf(redm[2], redm[3]));

  float sum = 0.f;
  if (active) {
#pragma unroll
    for (int e = 0; e < 8; ++e) {
      float p = (j0 + e <= i) ? __expf(vals[e] - mx) : 0.f;
      vals[e] = p;
      sum += p;
    }
  }
#pragma unroll
  for (int off = 32; off; off >>= 1) sum += __shfl_xor(sum, off);
  __shared__ float reds[4];
  if ((t & 63) == 0) reds[t >> 6] = sum;
  __syncthreads();
  sum = reds[0] + reds[1] + reds[2] + reds[3];
  const float inv = 1.0f / sum;

  if (active) {
    bf16x8 o;
#pragma unroll
    for (int e = 0; e < 8; ++e) o[e] = (bf16_t)(vals[e] * inv);
    ((bf16x8*)row)[t] = o;
  }
}

// ---------------------------------------------------------------------------
// XCD-chunked bijective remap (requires nwg % 8 == 0; all grids comply).
// ---------------------------------------------------------------------------
__device__ __forceinline__ void xcd_remap(int& bx, int& by, int& bz) {
  const int gx = gridDim.x, gy = gridDim.y;
  int lin = (blockIdx.z * gy + blockIdx.y) * gx + blockIdx.x;
  const int nwg = gx * gy * (int)gridDim.z;
  lin = (lin & 7) * (nwg >> 3) + (lin >> 3);
  bx = lin % gx;
  const int rem = lin / gx;
  by = rem % gy;
  bz = rem / gy;
}

// ---------------------------------------------------------------------------
// 128 x (NF*32) GEMM core, BK=64, XOR-swizzled LDS (R10/R11-proven, now
// templated on B-tile width). NF=4 -> 128-wide (32 KB LDS), NF=2 -> 64-wide
// (24 KB LDS, doubles grid for residency-starved dispatches).
// ---------------------------------------------------------------------------
template <int NF>
__device__ __forceinline__ void gemm_core(char* smem,
                                          const bf16_t* __restrict__ A,
                                          const bf16_t* __restrict__ B,
                                          int K, int KT, int m0, int n0,
                                          f32x4 (&acc)[4][NF]) {
  char* const asb = smem;
  char* const bsb = smem + 16384;
  const int t = threadIdx.x;
  const int l = t & 63;
  const int w = t >> 6;
  const int wr = w >> 1, wc = w & 1;
  const int r16 = l & 15, kg = l >> 4;

  const bf16_t* a_src[4];
  const bf16_t* b_src[NF];
#pragma unroll
  for (int i = 0; i < 4; ++i) {
    const int c = i * 256 + t;
    const int row = c >> 3;
    const int sl = (c & 7) ^ (row & 7);
    a_src[i] = A + (long)(m0 + row) * K + sl * 8;
  }
#pragma unroll
  for (int i = 0; i < NF; ++i) {
    const int c = i * 256 + t;
    const int row = c >> 3;
    const int sl = (c & 7) ^ (row & 7);
    b_src[i] = B + (long)(n0 + row) * K + sl * 8;
  }

  int aoff[2][4], boff[2][NF];
#pragma unroll
  for (int kp = 0; kp < 2; ++kp) {
#pragma unroll
    for (int mi = 0; mi < 4; ++mi) {
      const int ra = wr * 64 + mi * 16 + r16;
      aoff[kp][mi] = ra * 128 + ((kp * 4 + kg) ^ (ra & 7)) * 16;
    }
#pragma unroll
    for (int ni = 0; ni < NF; ++ni) {
      const int rb = wc * (NF * 16) + ni * 16 + r16;
      boff[kp][ni] = rb * 128 + ((kp * 4 + kg) ^ (rb & 7)) * 16;
    }
  }

  for (int kt = 0; kt < KT; ++kt) {
    __syncthreads();
#pragma unroll
    for (int i = 0; i < 4; ++i) {
      GLD_LDS16(a_src[i], asb + i * 4096 + w * 1024);
      a_src[i] += 64;
    }
#pragma unroll
    for (int i = 0; i < NF; ++i) {
      GLD_LDS16(b_src[i], bsb + i * 4096 + w * 1024);
      b_src[i] += 64;
    }
    __syncthreads();

#pragma unroll
    for (int kp = 0; kp < 2; ++kp) {
      bf16x8 af[4], bfr[NF];
#pragma unroll
      for (int mi = 0; mi < 4; ++mi) af[mi] = *(const bf16x8*)(asb + aoff[kp][mi]);
#pragma unroll
      for (int ni = 0; ni < NF; ++ni) bfr[ni] = *(const bf16x8*)(bsb + boff[kp][ni]);
#pragma unroll
      for (int mi = 0; mi < 4; ++mi)
#pragma unroll
        for (int ni = 0; ni < NF; ++ni)
          acc[mi][ni] =
              __builtin_amdgcn_mfma_f32_16x16x32_bf16(af[mi], bfr[ni], acc[mi][ni], 0, 0, 0);
    }
  }
}

// ---------------------------------------------------------------------------
// Generic GEMM kernel: C = alpha*A[M,K]*B[N,K]^T (+bias). Tile 128 x (NF*32).
// EPI 0=fp32, 1=bf16. KBOUND: K limited to n0+NF*32 (PV causality).
// ---------------------------------------------------------------------------
template <int NF, int EPI, bool BIAS, bool KBOUND>
__global__ __launch_bounds__(256, 4) void gemm_bt(const bf16_t* __restrict__ Ag,
                                                  const bf16_t* __restrict__ Bg,
                                                  const float* __restrict__ bias,
                                                  void* __restrict__ Cout,
                                                  int N, int K, float alpha,
                                                  long sAb, long sBb, long sCb, int eltC) {
  int bx, by, bz;
  xcd_remap(bx, by, bz);
  const int m0 = by << 7, n0 = bx * (NF * 32);

  int KT = K >> 6;
  if (KBOUND) {
    const int kb = (n0 + NF * 32) >> 6;
    if (kb < KT) KT = kb;
  }

  __shared__ __align__(16) char smem[16384 + NF * 4096];
  f32x4 acc[4][NF] = {};
  gemm_core<NF>(smem, Ag + (long)bz * sAb, Bg + (long)bz * sBb, K, KT, m0, n0, acc);

  const int t = threadIdx.x;
  const int l = t & 63;
  const int w = t >> 6;
  const int wr = w >> 1, wc = w & 1;
  const int rowbase = m0 + wr * 64 + ((l >> 4) << 2);
  const int colbase = n0 + wc * (NF * 16) + (l & 15);
  if constexpr (EPI == 0) {
    float* C = (float*)((char*)Cout + (long)bz * sCb * eltC);
#pragma unroll
    for (int mi = 0; mi < 4; ++mi)
#pragma unroll
      for (int ni = 0; ni < NF; ++ni) {
        const int col = colbase + ni * 16;
        float badd = 0.f;
        if constexpr (BIAS) badd = bias[col];
#pragma unroll
        for (int j = 0; j < 4; ++j)
          C[(long)(rowbase + mi * 16 + j) * N + col] = acc[mi][ni][j] * alpha + badd;
      }
  } else {
    bf16_t* C = (bf16_t*)((char*)Cout + (long)bz * sCb * eltC);
#pragma unroll
    for (int mi = 0; mi < 4; ++mi)
#pragma unroll
      for (int ni = 0; ni < NF; ++ni) {
        const int col = colbase + ni * 16;
        float badd = 0.f;
        if constexpr (BIAS) badd = bias[col];
#pragma unroll
        for (int j = 0; j < 4; ++j)
          C[(long)(rowbase + mi * 16 + j) * N + col] = (bf16_t)(acc[mi][ni][j] * alpha + badd);
      }
  }
}

// ---------------------------------------------------------------------------
// Scores: 128x64 tiles, triangle-paired rectangular grid (17,16,4) = 1088
// blocks, all causal-active (272 tiles/batch; bijection verified: direct
// branch i<=2j+1 -> (j,i); complement (j<=7, i>=2j+2) -> (15-j, i+15-2j)).
// S[z] = qp[z] x kp[z]^T * (1/32).
// ---------------------------------------------------------------------------
__global__ __launch_bounds__(256, 4) void gemm_scores(const bf16_t* __restrict__ qp,
                                                      const bf16_t* __restrict__ kp,
                                                      bf16_t* __restrict__ S,
                                                      long nd, long nn) {
  int bx, by, bz;
  xcd_remap(bx, by, bz);
  int r, c;
  if (bx <= 2 * by + 1) { r = by; c = bx; }
  else { r = 15 - by; c = bx + 15 - 2 * by; }
  const int m0 = r << 7, n0 = c << 6;

  __shared__ __align__(16) char smem[24576];
  f32x4 acc[4][2] = {};
  gemm_core<2>(smem, qp + (long)bz * nd, kp + (long)bz * nd, 1024, 16, m0, n0, acc);

  const int t = threadIdx.x;
  const int l = t & 63;
  const int w = t >> 6;
  const int wr = w >> 1, wc = w & 1;
  const int rowbase = m0 + wr * 64 + ((l >> 4) << 2);
  const int colbase = n0 + wc * 32 + (l & 15);
  bf16_t* C = S + (long)bz * nn;
#pragma unroll
  for (int mi = 0; mi < 4; ++mi)
#pragma unroll
    for (int ni = 0; ni < 2; ++ni) {
      const int col = colbase + ni * 16;
#pragma unroll
      for (int j = 0; j < 4; ++j)
        C[(long)(rowbase + mi * 16 + j) * 2048 + col] = (bf16_t)(acc[mi][ni][j] * 0.03125f);
    }
}

// ---------------------------------------------------------------------------
// Fused QKV projections (R11-proven, 128x128 core). z<2: normal store;
// z==2: V transposed into vpT via chunk-XOR-swizzled LDS transpose.
// ---------------------------------------------------------------------------
struct Qkv3Args {
  const bf16_t* A[3];
  const bf16_t* W[3];
  const float* bias[3];
  bf16_t* C[3];
};

__global__ __launch_bounds__(256, 4) void qkv3(Qkv3Args ga, int N, int K) {
  int bx, by, bz;
  xcd_remap(bx, by, bz);
  const int m0 = by << 7, n0 = bx << 7;

  __shared__ __align__(16) char smem[32768];
  f32x4 acc[4][4] = {};
  gemm_core<4>(smem, ga.A[bz], ga.W[bz], K, K >> 6, m0, n0, acc);

  const float* __restrict__ bias = ga.bias[bz];
  const int t = threadIdx.x;
  const int l = t & 63;
  const int w = t >> 6;
  const int wr = w >> 1, wc = w & 1;
  const int r16 = l & 15, kg = l >> 4;

  if (bz < 2) {
    bf16_t* C = ga.C[bz];
    const int rowbase = m0 + wr * 64 + kg * 4;
    const int colbase = n0 + wc * 64 + r16;
#pragma unroll
    for (int mi = 0; mi < 4; ++mi)
#pragma unroll
      for (int ni = 0; ni < 4; ++ni) {
        const int col = colbase + ni * 16;
        const float badd = bias[col];
#pragma unroll
        for (int j = 0; j < 4; ++j)
          C[(long)(rowbase + mi * 16 + j) * N + col] = (bf16_t)(acc[mi][ni][j] + badd);
      }
  } else {
    __syncthreads();
    char* tt = smem;  // [128 rows(d)][256 B], phys chunk = logical^(lc&7)
#pragma unroll
    for (int mi = 0; mi < 4; ++mi)
#pragma unroll
      for (int ni = 0; ni < 4; ++ni) {
        const int lc = wc * 64 + ni * 16 + r16;
        const int lrb = (wr * 64 + mi * 16 + kg * 4) * 2;
        const float badd = bias[n0 + lc];
        bf16x4 o;
#pragma unroll
        for (int j = 0; j < 4; ++j) o[j] = (bf16_t)(acc[mi][ni][j] + badd);
        *(bf16x4*)(tt + lc * 256 + (lrb ^ ((lc & 7) << 4))) = o;
      }
    __syncthreads();
    bf16_t* C = ga.C[2];
    const int batch = m0 >> 11, nb = m0 & 2047;
#pragma unroll
    for (int i = 0; i < 8; ++i) {
      const int c = i * 256 + t;
      const int lc = c >> 4, ch = c & 15;
      *(bf16x8*)(C + (long)batch * (2048 * 1024) + (long)(n0 + lc) * 2048 + nb + ch * 8) =
          *(const bf16x8*)(tt + lc * 256 + ((ch * 16) ^ ((lc & 7) << 4)));
    }
  }
}

// ---------------------------------------------------------------------------
extern "C" void kernel_launch(void* const* d_in, const int* in_sizes, int n_in,
                              void* d_out, int out_size, void* d_ws, size_t ws_size,
                              hipStream_t stream) {
  const int b = 4, n = 2048, d = 1024;
  const long nd  = (long)n * d;
  const long bn  = (long)b * n;
  const long bnd = bn * d;
  const long ddl = (long)d * d;
  const long nn  = (long)n * n;

  const float* q  = (const float*)d_in[0];
  const float* k  = (const float*)d_in[1];
  const float* v  = (const float*)d_in[2];
  const float* Wq = (const float*)d_in[3];
  const float* bq = (const float*)d_in[4];
  const float* Wk = (const float*)d_in[5];
  const float* bk = (const float*)d_in[6];
  const float* Wv = (const float*)d_in[7];
  const float* bv = (const float*)d_in[8];
  const float* Wo = (const float*)d_in[9];
  const float* bo = (const float*)d_in[10];

  bf16_t* ws  = (bf16_t*)d_ws;
  bf16_t* qB  = ws;
  bf16_t* kB  = qB + bnd;
  bf16_t* vB  = kB + bnd;
  bf16_t* WqB = vB + bnd;
  bf16_t* WkB = WqB + ddl;
  bf16_t* WvB = WkB + ddl;
  bf16_t* WoB = WvB + ddl;
  bf16_t* qpB = WoB + ddl;
  bf16_t* kpB = qpB + bnd;
  bf16_t* vpT = kpB + bnd;
  bf16_t* S   = vpT + bnd;
  bf16_t* yT  = S + (long)b * nn;
  const size_t need = (size_t)(7 * bnd + 4 * ddl + (long)b * nn) * 2;
  if (ws_size < need) return;

  dim3 blk(256);

  // fp32 -> bf16 converts
  CvtArgs ca;
  ca.src[0] = q;  ca.dst[0] = qB;  ca.n4[0] = bnd / 4;
  ca.src[1] = k;  ca.dst[1] = kB;  ca.n4[1] = bnd / 4;
  ca.src[2] = v;  ca.dst[2] = vB;  ca.n4[2] = bnd / 4;
  ca.src[3] = Wq; ca.dst[3] = WqB; ca.n4[3] = ddl / 4;
  ca.src[4] = Wk; ca.dst[4] = WkB; ca.n4[4] = ddl / 4;
  ca.src[5] = Wv; ca.dst[5] = WvB; ca.n4[5] = ddl / 4;
  ca.src[6] = Wo; ca.dst[6] = WoB; ca.n4[6] = ddl / 4;
  cvt_all<<<dim3(512, 7), blk, 0, stream>>>(ca);

  // fused QKV projections: grid (8, 64, 3) = 1536 blocks
  Qkv3Args qa;
  qa.A[0] = qB; qa.W[0] = WqB; qa.bias[0] = bq; qa.C[0] = qpB;
  qa.A[1] = kB; qa.W[1] = WkB; qa.bias[1] = bk; qa.C[1] = kpB;
  qa.A[2] = vB; qa.W[2] = WvB; qa.bias[2] = bv; qa.C[2] = vpT;
  qkv3<<<dim3(d / 128, bn / 128, 3), blk, 0, stream>>>(qa, d, d);

  // scores: 128x64 tiles, triangle-paired grid (17,16,4) = 1088 blocks
  gemm_scores<<<dim3(17, 16, b), blk, 0, stream>>>(qpB, kpB, S, nd, nn);

  // causal softmax in place (bounded)
  softmax_causal<<<dim3(n, b), blk, 0, stream>>>(S, n, nn);

  // yT[z] = vpT[z] x P[z]^T, 128x64 tiles: grid (32, 8, 4) = 1024 blocks
  gemm_bt<2, 1, false, true><<<dim3(n / 64, d / 128, b), blk, 0, stream>>>(
      vpT, S, nullptr, yT, n, n, 1.f, nd, nn, nd, 2);

  // out = y2 x Wo^T + bo, 128x64 tiles: grid (16, 64, 1) = 1024 blocks
  gemm_bt<2, 0, true, false><<<dim3(d / 64, bn / 128, 1), blk, 0, stream>>>(
      yT, WoB, bo, (float*)d_out, d, d, 1.f, 0, 0, 0, 4);
}